// Round 14
// baseline (225.568 us; speedup 1.0000x reference)
//
#include <hip/hip_runtime.h>
#include <stdint.h>

typedef unsigned short u16;
typedef unsigned char u8;
typedef __bf16 bf16_t;
typedef bf16_t bf16x8 __attribute__((ext_vector_type(8)));
typedef float f32x4 __attribute__((ext_vector_type(4)));
typedef u16 u16x4 __attribute__((ext_vector_type(4)));
typedef u16 u16x8 __attribute__((ext_vector_type(8)));

__device__ __forceinline__ u16 f2bf(float f) {
  union { float f; uint32_t u; } v;
  v.f = f;
  uint32_t u = v.u + 0x7fffu + ((v.u >> 16) & 1u);
  return (u16)(u >> 16);
}

__device__ __forceinline__ float bf2f(u16 x) {
  union { uint32_t u; float f; } v;
  v.u = ((uint32_t)x) << 16;
  return v.f;
}

__device__ __forceinline__ void gload16(const void* g, void* l) {
  __builtin_amdgcn_global_load_lds(
      (__attribute__((address_space(1))) void*)g,
      (__attribute__((address_space(3))) void*)l, 16, 0, 0);
}

__device__ __forceinline__ f32x4 mfma16(bf16x8 a, bf16x8 b, f32x4 c) {
  return __builtin_amdgcn_mfma_f32_16x16x32_bf16(a, b, c, 0, 0, 0);
}

// ---------- merged fp32->bf16 convert (prim, ctx) + weight transpose ----------
__global__ __launch_bounds__(256) void cvt_wt(
    const float* __restrict__ prim, u16* __restrict__ prim_bf,
    const float* __restrict__ ctx, u16* __restrict__ ctx_bf,
    const float* __restrict__ Wq, const float* __restrict__ Wk,
    const float* __restrict__ Wv, u16* __restrict__ Oq,
    u16* __restrict__ Ok, u16* __restrict__ Ov) {
  int b = blockIdx.x;
  if (b < 2048) {
    const float* in = (b < 1024) ? prim : ctx;
    u16* out = (b < 1024) ? prim_bf : ctx_bf;
    int bb = b & 1023;
    int i = bb * 256 + threadIdx.x;
    const int n4 = 2097152;
    for (; i < n4; i += 1024 * 256) {
      float4 v = *((const float4*)in + i);
      u16x4 o;
      o.x = f2bf(v.x); o.y = f2bf(v.y); o.z = f2bf(v.z); o.w = f2bf(v.w);
      *((u16x4*)out + i) = o;
    }
  } else {
    int tb = b - 2048;
    int zi = tb >> 10, rem = tb & 1023;
    const float* W = zi == 0 ? Wq : (zi == 1 ? Wk : Wv);
    u16* O = zi == 0 ? Oq : (zi == 1 ? Ok : Ov);
    __shared__ float t[32][33];
    int x = threadIdx.x & 31, y = threadIdx.x >> 5;
    int n0 = (rem & 31) * 32, k0 = (rem >> 5) * 32;
#pragma unroll
    for (int i = 0; i < 32; i += 8)
      t[y + i][x] = W[(size_t)(k0 + y + i) * 1024 + n0 + x];
    __syncthreads();
#pragma unroll
    for (int i = 0; i < 32; i += 8)
      O[(size_t)(n0 + y + i) * 1024 + k0 + x] = f2bf(t[x][y + i]);
  }
}

// ---------------- 256x256 bf16 GEMM body, BK=32, 4-buffer depth-3 pipeline -----------
// 512 threads = 8 waves (2M x 4N; wave tile 128x64). LDS = 4 bufs x (256x32) x 2 ops
// = 128 KB, passed in from the kernel so all instantiations share one allocation.
// Per 32-K tile: 12 ds_read_b128 + stage(t+3) (4 gloads) + lgkmcnt(0) + 32 MFMA +
// vmcnt(8) + ONE barrier. Liveness: stage at t targets buf[(t+3)&3]=buf[(t-1)&3],
// fully read before t-1's end barrier; vmcnt(8) at t-end drains exactly t+1's 4
// loads (newest 8 = t+2's + t+3's). In-flight never below 8 instr/wave.
// Swizzle: 16B slot ^= (row>>2)&3 (inverse on global source, same XOR on ds_read)
// -> 2-way bank conflict (free).
template <typename CT>
__device__ __forceinline__ void gemm_body(
    u16* aL, u16* bL,
    const u16* __restrict__ A, const u16* __restrict__ Bt,
    const float* __restrict__ biasCol, const float* __restrict__ biasRow,
    CT* __restrict__ C, int bm, int bn, int K, int lda, int ldb, int ldc) {
  int tid = threadIdx.x;
  int lane = tid & 63, w = tid >> 6;
  int l15 = lane & 15, g = lane >> 4;
  int wr = w >> 2, wc = w & 3;
  int NT = K >> 5;

  f32x4 acc[8][4] = {};

  auto stageA = [&](int buf, int tk) {
    int k0 = tk * 32;
#pragma unroll
    for (int l = 0; l < 2; ++l) {
      int u = l * 512 + tid;
      int row = u >> 2;
      int slot = (u & 3) ^ ((row >> 2) & 3);
      gload16(A + (size_t)(bm + row) * lda + k0 + slot * 8,
              aL + buf * 8192 + row * 32 + (u & 3) * 8);
    }
  };
  auto stageB = [&](int buf, int tk) {
    int k0 = tk * 32;
#pragma unroll
    for (int l = 0; l < 2; ++l) {
      int u = l * 512 + tid;
      int row = u >> 2;
      int slot = (u & 3) ^ ((row >> 2) & 3);
      gload16(Bt + (size_t)(bn + row) * ldb + k0 + slot * 8,
              bL + buf * 8192 + row * 32 + (u & 3) * 8);
    }
  };
  auto ldA = [&](int buf, int m) -> bf16x8 {
    int row = wr * 128 + m * 16 + l15;
    int col = (g ^ ((row >> 2) & 3)) * 8;
    return *(const bf16x8*)(aL + buf * 8192 + row * 32 + col);
  };
  auto ldB = [&](int buf, int j) -> bf16x8 {
    int row = wc * 64 + j * 16 + l15;
    int col = (g ^ ((row >> 2) & 3)) * 8;
    return *(const bf16x8*)(bL + buf * 8192 + row * 32 + col);
  };

  // prologue: stage tiles 0,1,2 (12 loads); drain tile 0's 4, keep 8 in flight
  stageA(0, 0); stageB(0, 0);
  stageA(1, NT > 1 ? 1 : 0); stageB(1, NT > 1 ? 1 : 0);
  stageA(2, NT > 2 ? 2 : 0); stageB(2, NT > 2 ? 2 : 0);
  asm volatile("s_waitcnt vmcnt(8)" ::: "memory");
  __builtin_amdgcn_s_barrier();

  for (int t = 0; t < NT; ++t) {
    int buf = t & 3;
    int tn3 = (t + 3 < NT) ? t + 3 : NT - 1;
    int bn3 = (t + 3) & 3;
    bf16x8 af[8], bfv[4];
#pragma unroll
    for (int m = 0; m < 8; ++m) af[m] = ldA(buf, m);
#pragma unroll
    for (int j = 0; j < 4; ++j) bfv[j] = ldB(buf, j);
    stageA(bn3, tn3);
    stageB(bn3, tn3);
    asm volatile("s_waitcnt lgkmcnt(0)" ::: "memory");
    __builtin_amdgcn_sched_barrier(0);
    __builtin_amdgcn_s_setprio(1);
#pragma unroll
    for (int m = 0; m < 8; ++m)
#pragma unroll
      for (int j = 0; j < 4; ++j) acc[m][j] = mfma16(af[m], bfv[j], acc[m][j]);
    __builtin_amdgcn_s_setprio(0);
    asm volatile("s_waitcnt vmcnt(8)" ::: "memory");
    __builtin_amdgcn_s_barrier();
  }

  // epilogue
#pragma unroll
  for (int mi = 0; mi < 8; ++mi) {
    int row = bm + wr * 128 + mi * 16 + g * 4;
#pragma unroll
    for (int j = 0; j < 4; ++j) {
      int col = bn + wc * 64 + j * 16 + l15;
      float bcv = biasCol ? biasCol[col] : 0.0f;
#pragma unroll
      for (int rr = 0; rr < 4; ++rr) {
        float brv = biasRow ? biasRow[row + rr] : 0.0f;
        float v = acc[mi][j][rr] + bcv + brv;
        if constexpr (sizeof(CT) == 1) {
          unsigned int p = __builtin_amdgcn_cvt_pk_fp8_f32(v, v, 0, false);
          C[(size_t)(row + rr) * ldc + col] = (CT)(p & 0xff);
        } else if constexpr (sizeof(CT) == 2) {
          C[(size_t)(row + rr) * ldc + col] = f2bf(v);
        } else {
          C[(size_t)(row + rr) * ldc + col] = v;
        }
      }
    }
  }
}

// ---- proj3: z=0 Q->fp8, z=1 K->fp8, z=2 V^T->bf16  (384 blocks) ----
__global__ __launch_bounds__(512, 2) void proj3(
    const u16* __restrict__ prim_ctx, const u16* __restrict__ wqk,
    const u16* __restrict__ wvt, const u16* __restrict__ ctx_bf,
    const float* __restrict__ bq, const float* __restrict__ bk,
    const float* __restrict__ bv,
    u8* __restrict__ qk8, u16* __restrict__ vt) {
  __shared__ u16 smem[2 * 4 * 8192];       // 128 KB shared by all instantiations
  u16* aL = smem;
  u16* bL = smem + 4 * 8192;
  int bz = blockIdx.z;
  if (bz < 2) {
    gemm_body<u8>(aL, bL,
                  prim_ctx + (size_t)bz * 8192 * 1024,
                  wqk + (size_t)bz * 1024 * 1024,
                  bz ? bk : bq, nullptr,
                  qk8 + (size_t)bz * 8192 * 1024,
                  blockIdx.x * 256, blockIdx.y * 256, 1024, 1024, 1024, 1024);
  } else {
    int lin = blockIdx.x + 32 * blockIdx.y;
    gemm_body<u16>(aL, bL, wvt, ctx_bf, nullptr, bv, vt,
                   (lin & 3) * 256, (lin >> 2) * 256, 1024, 1024, 1024, 8192);
  }
}

// ---- fp8 S-GEMM (r13-verbatim, proven): S = Q8 @ K8^T, batched, bf16 out ----
__global__ __launch_bounds__(512, 2) void gemm_s8(
    const u8* __restrict__ A, const u8* __restrict__ Bt, u16* __restrict__ C) {
  const int lda = 1024, ldb = 1024, ldc = 2048, K = 1024;
  const u8* Ab = A + (size_t)blockIdx.z * 2048 * 1024;
  const u8* Bb = Bt + (size_t)blockIdx.z * 2048 * 1024;
  u16* Cb = C + (size_t)blockIdx.z * 2048 * 2048;
  int bm = blockIdx.x * 256, bn = blockIdx.y * 256;

  __shared__ u8 aLds[2][256 * 64];
  __shared__ u8 bLds[2][256 * 64];
  int tid = threadIdx.x;
  int lane = tid & 63, w = tid >> 6;
  int l15 = lane & 15, g = lane >> 4;
  int wr = w >> 2, wc = w & 3;
  int NT = K >> 6;

  f32x4 acc[8][4] = {};

  auto stageA = [&](int buf, int h, int tk) {
    int k0 = tk * 64;
    int r = tid >> 2;
    int row = h * 64 + (r & 63) + (r >> 6) * 128;
    int cd = (tid & 3) * 16;
    int cs = cd ^ ((row & 3) * 16);
    gload16(Ab + (size_t)(bm + row) * lda + k0 + cs, &aLds[buf][row * 64 + cd]);
  };
  auto stageB = [&](int buf, int x, int tk) {
    int k0 = tk * 64;
    int row = x * 128 + (tid >> 2);
    int cd = (tid & 3) * 16;
    int cs = cd ^ ((row & 3) * 16);
    gload16(Bb + (size_t)(bn + row) * ldb + k0 + cs, &bLds[buf][row * 64 + cd]);
  };
  auto ldA = [&](int buf, int m, int kc) -> long {
    int row = wr * 128 + m * 16 + l15;
    int colb = (kc * 32 + g * 8) ^ ((row & 3) * 16);
    return *(const long*)&aLds[buf][row * 64 + colb];
  };
  auto ldB = [&](int buf, int j, int kc) -> long {
    int row = wc * 64 + j * 16 + l15;
    int colb = (kc * 32 + g * 8) ^ ((row & 3) * 16);
    return *(const long*)&bLds[buf][row * 64 + colb];
  };

  stageA(0, 0, 0);
  stageB(0, 0, 0);
  stageB(0, 1, 0);
  stageA(0, 1, 0);
  int t1c = NT > 1 ? 1 : 0;
  stageA(1, 0, t1c);
  stageB(1, 0, t1c);
  asm volatile("s_waitcnt vmcnt(3)" ::: "memory");
  __builtin_amdgcn_s_barrier();

  for (int t = 0; t < NT; ++t) {
    int cur = t & 1, nxt = cur ^ 1;
    int tn1 = (t + 1 < NT) ? t + 1 : NT - 1;
    int tn2 = (t + 2 < NT) ? t + 2 : NT - 1;
    long a0[4], b0[4], b1[4];

#pragma unroll
    for (int i = 0; i < 4; ++i) a0[i] = ldA(cur, i, 0);
#pragma unroll
    for (int j = 0; j < 4; ++j) b0[j] = ldB(cur, j, 0);
    stageB(nxt, 1, tn1);
    __builtin_amdgcn_s_barrier();
    asm volatile("s_waitcnt lgkmcnt(0)" ::: "memory");
    __builtin_amdgcn_sched_barrier(0);
    __builtin_amdgcn_s_setprio(1);
#pragma unroll
    for (int i = 0; i < 4; ++i)
#pragma unroll
      for (int j = 0; j < 4; ++j)
        acc[i][j] = __builtin_amdgcn_mfma_f32_16x16x32_fp8_fp8(a0[i], b0[j], acc[i][j], 0, 0, 0);
    __builtin_amdgcn_s_setprio(0);
    __builtin_amdgcn_s_barrier();

#pragma unroll
    for (int i = 0; i < 4; ++i) a0[i] = ldA(cur, i, 1);
#pragma unroll
    for (int j = 0; j < 4; ++j) b1[j] = ldB(cur, j, 1);
    stageA(nxt, 1, tn1);
    __builtin_amdgcn_s_barrier();
    asm volatile("s_waitcnt lgkmcnt(0)" ::: "memory");
    __builtin_amdgcn_sched_barrier(0);
    __builtin_amdgcn_s_setprio(1);
#pragma unroll
    for (int i = 0; i < 4; ++i)
#pragma unroll
      for (int j = 0; j < 4; ++j)
        acc[i][j] = __builtin_amdgcn_mfma_f32_16x16x32_fp8_fp8(a0[i], b1[j], acc[i][j], 0, 0, 0);
    __builtin_amdgcn_s_setprio(0);
    asm volatile("s_waitcnt vmcnt(4)" ::: "memory");
    __builtin_amdgcn_s_barrier();

#pragma unroll
    for (int i = 0; i < 4; ++i) a0[i] = ldA(cur, 4 + i, 0);
    stageA(cur, 0, tn2);
    __builtin_amdgcn_s_barrier();
    asm volatile("s_waitcnt lgkmcnt(0)" ::: "memory");
    __builtin_amdgcn_sched_barrier(0);
    __builtin_amdgcn_s_setprio(1);
#pragma unroll
    for (int i = 0; i < 4; ++i)
#pragma unroll
      for (int j = 0; j < 4; ++j)
        acc[4 + i][j] = __builtin_amdgcn_mfma_f32_16x16x32_fp8_fp8(a0[i], b0[j], acc[4 + i][j], 0, 0, 0);
    __builtin_amdgcn_s_setprio(0);
    __builtin_amdgcn_s_barrier();

#pragma unroll
    for (int i = 0; i < 4; ++i) a0[i] = ldA(cur, 4 + i, 1);
    stageB(cur, 0, tn2);
    __builtin_amdgcn_s_barrier();
    asm volatile("s_waitcnt lgkmcnt(0)" ::: "memory");
    __builtin_amdgcn_sched_barrier(0);
    __builtin_amdgcn_s_setprio(1);
#pragma unroll
    for (int i = 0; i < 4; ++i)
#pragma unroll
      for (int j = 0; j < 4; ++j)
        acc[4 + i][j] = __builtin_amdgcn_mfma_f32_16x16x32_fp8_fp8(a0[i], b1[j], acc[4 + i][j], 0, 0, 0);
    __builtin_amdgcn_s_setprio(0);
    asm volatile("s_waitcnt vmcnt(3)" ::: "memory");
    __builtin_amdgcn_s_barrier();
  }

#pragma unroll
  for (int mi = 0; mi < 8; ++mi) {
    int row = bm + wr * 128 + mi * 16 + g * 4;
#pragma unroll
    for (int j = 0; j < 4; ++j) {
      int col = bn + wc * 64 + j * 16 + l15;
#pragma unroll
      for (int rr = 0; rr < 4; ++rr)
        Cb[(size_t)(row + rr) * ldc + col] = f2bf(acc[mi][j][rr]);
    }
  }
}

// ---- generic batched bf16 GEMM (PV) ----
template <typename CT>
__global__ __launch_bounds__(512, 2) void gemm256(
    const u16* __restrict__ A, const u16* __restrict__ Bt,
    CT* __restrict__ C, int K, int lda, int ldb, int ldc,
    long long bsA, long long bsB, long long bsC) {
  __shared__ u16 smem[2 * 4 * 8192];
  gemm_body<CT>(smem, smem + 4 * 8192,
                A + (size_t)blockIdx.z * bsA, Bt + (size_t)blockIdx.z * bsB,
                nullptr, nullptr, C + (size_t)blockIdx.z * bsC,
                blockIdx.x * 256, blockIdx.y * 256, K, lda, ldb, ldc);
}

// ---------------- fused mask + row softmax ----------------
__global__ __launch_bounds__(256) void softmax_mask(
    const u16* __restrict__ S, const float* __restrict__ mask, u16* __restrict__ P) {
  const float C1 = 0.04508422f;    // log2(e)/32
  const float C2 = -1.4426950e9f;  // -1e9*log2(e)
  int wid = (blockIdx.x * blockDim.x + threadIdx.x) >> 6;
  int lane = threadIdx.x & 63;
  size_t base = (size_t)wid * 2048;
  const u16* sp = S + base;
  const float* mp = mask + base;

  float a[32];
#pragma unroll
  for (int pass = 0; pass < 4; ++pass) {
    int e0 = pass * 512 + lane * 8;
    u16x8 sv = *(const u16x8*)(sp + e0);
    float4 m0 = *(const float4*)(mp + e0);
    float4 m1 = *(const float4*)(mp + e0 + 4);
    a[pass * 8 + 0] = bf2f(sv[0]) * C1 + m0.x * C2;
    a[pass * 8 + 1] = bf2f(sv[1]) * C1 + m0.y * C2;
    a[pass * 8 + 2] = bf2f(sv[2]) * C1 + m0.z * C2;
    a[pass * 8 + 3] = bf2f(sv[3]) * C1 + m0.w * C2;
    a[pass * 8 + 4] = bf2f(sv[4]) * C1 + m1.x * C2;
    a[pass * 8 + 5] = bf2f(sv[5]) * C1 + m1.y * C2;
    a[pass * 8 + 6] = bf2f(sv[6]) * C1 + m1.z * C2;
    a[pass * 8 + 7] = bf2f(sv[7]) * C1 + m1.w * C2;
  }
  float m = a[0];
#pragma unroll
  for (int i = 1; i < 32; ++i) m = fmaxf(m, a[i]);
#pragma unroll
  for (int off = 32; off >= 1; off >>= 1) m = fmaxf(m, __shfl_xor(m, off));

  float s = 0.0f;
#pragma unroll
  for (int i = 0; i < 32; ++i) {
    a[i] = exp2f(a[i] - m);
    s += a[i];
  }
#pragma unroll
  for (int off = 32; off >= 1; off >>= 1) s += __shfl_xor(s, off);
  float inv = 1.0f / s;

  u16* pp = P + base;
#pragma unroll
  for (int pass = 0; pass < 4; ++pass) {
    int e0 = pass * 512 + lane * 8;
    u16x8 o;
#pragma unroll
    for (int j = 0; j < 8; ++j) o[j] = f2bf(a[pass * 8 + j] * inv);
    *(u16x8*)(pp + e0) = o;
  }
}

extern "C" void kernel_launch(void* const* d_in, const int* in_sizes, int n_in,
                              void* d_out, int out_size, void* d_ws, size_t ws_size,
                              hipStream_t stream) {
  const float* primary = (const float*)d_in[0];
  const float* ctx     = (const float*)d_in[1];
  const float* mask    = (const float*)d_in[2];
  const float* Wq      = (const float*)d_in[3];
  const float* bq      = (const float*)d_in[4];
  const float* Wk      = (const float*)d_in[5];
  const float* bk      = (const float*)d_in[6];
  const float* Wv      = (const float*)d_in[7];
  const float* bv      = (const float*)d_in[8];
  float* out = (float*)d_out;

  char* ws = (char*)d_ws;
  // Layout (peak 90.2 MB):
  //   [0, 8.4M)     q8 (fp8)   } P bf16 overlays [0, 33.5M) after S
  //   [8.4, 16.8M)  k8 (fp8)   }
  //   [33.5, 50.3M) vtbf
  //   [50.3, 67M)   prim_bf    } S bf16 overlays [50.3, 83.9M) after proj3
  //   [67, 83.9M)   ctx_bf     }
  //   [83.9, 90.2M) wqt/wkt/wvt
  u8*  qk8     = (u8*)(ws);
  u16* vtbf    = (u16*)(ws + 2 * 16777216);
  u16* prim_bf = (u16*)(ws + 3 * 16777216);
  u16* ctx_bf  = (u16*)(ws + 4 * 16777216);
  u16* wqt     = (u16*)(ws + 5 * 16777216);
  u16* wkt     = (u16*)(ws + 5 * 16777216 + 2097152);
  u16* wvt     = (u16*)(ws + 5 * 16777216 + 2 * 2097152);
  u16* sbf     = (u16*)(ws + 3 * 16777216);
  u16* pbf     = (u16*)(ws);

  cvt_wt<<<5120, 256, 0, stream>>>(primary, prim_bf, ctx, ctx_bf,
                                   Wq, Wk, Wv, wqt, wkt, wvt);
  // Q (fp8), K (fp8), V^T (bf16) in one dispatch (384 blocks)
  proj3<<<dim3(32, 4, 3), 512, 0, stream>>>(
      prim_bf, wqt, wvt, ctx_bf, bq, bk, bv, qk8, vtbf);
  // S = Q8 @ K8^T -> sbf [4][2048 x 2048] bf16 (fp8 staging, half bytes)
  gemm_s8<<<dim3(8, 8, 4), 512, 0, stream>>>(qk8, qk8 + 8192 * 1024, sbf);
  // P = softmax(S*C1 + mask*C2) -> pbf
  softmax_mask<<<2048, 256, 0, stream>>>(sbf, mask, pbf);
  // O = P @ (V^T)^T -> out fp32 [4][2048 x 1024]
  gemm256<float><<<dim3(8, 4, 4), 512, 0, stream>>>(
      pbf, vtbf, out, 2048, 2048, 8192, 1024,
      2048 * 2048LL, 2048LL, 2048 * 1024LL);
}

// Round 15
// 206.801 us; speedup vs baseline: 1.0908x; 1.0908x over previous
//
#include <hip/hip_runtime.h>
#include <stdint.h>

typedef unsigned short u16;
typedef unsigned char u8;
typedef __bf16 bf16_t;
typedef bf16_t bf16x8 __attribute__((ext_vector_type(8)));
typedef float f32x4 __attribute__((ext_vector_type(4)));
typedef u16 u16x4 __attribute__((ext_vector_type(4)));
typedef u16 u16x8 __attribute__((ext_vector_type(8)));

__device__ __forceinline__ u16 f2bf(float f) {
  union { float f; uint32_t u; } v;
  v.f = f;
  uint32_t u = v.u + 0x7fffu + ((v.u >> 16) & 1u);
  return (u16)(u >> 16);
}

__device__ __forceinline__ float bf2f(u16 x) {
  union { uint32_t u; float f; } v;
  v.u = ((uint32_t)x) << 16;
  return v.f;
}

__device__ __forceinline__ void gload16(const void* g, void* l) {
  __builtin_amdgcn_global_load_lds(
      (__attribute__((address_space(1))) void*)g,
      (__attribute__((address_space(3))) void*)l, 16, 0, 0);
}

__device__ __forceinline__ f32x4 mfma16(bf16x8 a, bf16x8 b, f32x4 c) {
  return __builtin_amdgcn_mfma_f32_16x16x32_bf16(a, b, c, 0, 0, 0);
}

// ---------- merged fp32->bf16 convert (prim, ctx) + weight transpose ----------
__global__ __launch_bounds__(256) void cvt_wt(
    const float* __restrict__ prim, u16* __restrict__ prim_bf,
    const float* __restrict__ ctx, u16* __restrict__ ctx_bf,
    const float* __restrict__ Wq, const float* __restrict__ Wk,
    const float* __restrict__ Wv, u16* __restrict__ Oq,
    u16* __restrict__ Ok, u16* __restrict__ Ov) {
  int b = blockIdx.x;
  if (b < 2048) {
    const float* in = (b < 1024) ? prim : ctx;
    u16* out = (b < 1024) ? prim_bf : ctx_bf;
    int bb = b & 1023;
    int i = bb * 256 + threadIdx.x;
    const int n4 = 2097152;
    for (; i < n4; i += 1024 * 256) {
      float4 v = *((const float4*)in + i);
      u16x4 o;
      o.x = f2bf(v.x); o.y = f2bf(v.y); o.z = f2bf(v.z); o.w = f2bf(v.w);
      *((u16x4*)out + i) = o;
    }
  } else {
    int tb = b - 2048;
    int zi = tb >> 10, rem = tb & 1023;
    const float* W = zi == 0 ? Wq : (zi == 1 ? Wk : Wv);
    u16* O = zi == 0 ? Oq : (zi == 1 ? Ok : Ov);
    __shared__ float t[32][33];
    int x = threadIdx.x & 31, y = threadIdx.x >> 5;
    int n0 = (rem & 31) * 32, k0 = (rem >> 5) * 32;
#pragma unroll
    for (int i = 0; i < 32; i += 8)
      t[y + i][x] = W[(size_t)(k0 + y + i) * 1024 + n0 + x];
    __syncthreads();
#pragma unroll
    for (int i = 0; i < 32; i += 8)
      O[(size_t)(n0 + y + i) * 1024 + k0 + x] = f2bf(t[x][y + i]);
  }
}

// ---------------- 256x256 8-phase bf16 GEMM body (round-4 schedule, proven) ----------
// LDS passed in (aL/bL each [2][256*64] u16) so instantiations share 128 KB.
template <typename CT>
__device__ __forceinline__ void gemm_body(
    u16* aL, u16* bL,
    const u16* __restrict__ A, const u16* __restrict__ Bt,
    const float* __restrict__ biasCol, const float* __restrict__ biasRow,
    CT* __restrict__ C, int bm, int bn, int K, int lda, int ldb, int ldc) {
  int tid = threadIdx.x;
  int lane = tid & 63, w = tid >> 6;
  int l15 = lane & 15, g = lane >> 4;
  int wr = w >> 2, wc = w & 3;
  int NT = K >> 6;

  f32x4 acc[8][4] = {};

  auto stageA = [&](int buf, int h, int tk) {
    int k0 = tk * 64;
    int r = tid >> 3, cd = (tid & 7) * 8;
    int cs = cd ^ ((r & 7) * 8);
    int row0 = h * 64 + r;
    gload16(A + (size_t)(bm + row0) * lda + k0 + cs, aL + buf * 16384 + row0 * 64 + cd);
    int row1 = row0 + 128;
    gload16(A + (size_t)(bm + row1) * lda + k0 + cs, aL + buf * 16384 + row1 * 64 + cd);
  };
  auto stageB = [&](int buf, int x, int tk) {
    int k0 = tk * 64;
#pragma unroll
    for (int l = 0; l < 2; ++l) {
      int u = l * 512 + tid;
      int r = u >> 3, cd = (u & 7) * 8;
      int cs = cd ^ ((r & 7) * 8);
      int row = x * 128 + r;
      gload16(Bt + (size_t)(bn + row) * ldb + k0 + cs, bL + buf * 16384 + row * 64 + cd);
    }
  };
  auto ldA = [&](int buf, int m, int kc) -> bf16x8 {
    int row = wr * 128 + m * 16 + l15;
    int col = (kc * 32 + g * 8) ^ ((row & 7) * 8);
    return *(const bf16x8*)(aL + buf * 16384 + row * 64 + col);
  };
  auto ldB = [&](int buf, int j, int kc) -> bf16x8 {
    int row = wc * 64 + j * 16 + l15;
    int col = (kc * 32 + g * 8) ^ ((row & 7) * 8);
    return *(const bf16x8*)(bL + buf * 16384 + row * 64 + col);
  };

  stageA(0, 0, 0);
  stageB(0, 0, 0);
  stageB(0, 1, 0);
  stageA(0, 1, 0);
  int t1c = NT > 1 ? 1 : 0;
  stageA(1, 0, t1c);
  stageB(1, 0, t1c);
  asm volatile("s_waitcnt vmcnt(6)" ::: "memory");
  __builtin_amdgcn_s_barrier();

  for (int t = 0; t < NT; ++t) {
    int cur = t & 1, nxt = cur ^ 1;
    int tn1 = (t + 1 < NT) ? t + 1 : NT - 1;
    int tn2 = (t + 2 < NT) ? t + 2 : NT - 1;
    bf16x8 a0[4], b0[4], b1[4];

    // ---- ph1: (grp0, kc0) ----
#pragma unroll
    for (int i = 0; i < 4; ++i) a0[i] = ldA(cur, i, 0);
#pragma unroll
    for (int j = 0; j < 4; ++j) b0[j] = ldB(cur, j, 0);
    stageB(nxt, 1, tn1);
    __builtin_amdgcn_s_barrier();
    asm volatile("s_waitcnt lgkmcnt(0)" ::: "memory");
    __builtin_amdgcn_sched_barrier(0);
    __builtin_amdgcn_s_setprio(1);
#pragma unroll
    for (int i = 0; i < 4; ++i)
#pragma unroll
      for (int j = 0; j < 4; ++j) acc[i][j] = mfma16(a0[i], b0[j], acc[i][j]);
    __builtin_amdgcn_s_setprio(0);
    __builtin_amdgcn_s_barrier();

    // ---- ph2: (grp0, kc1) ----
#pragma unroll
    for (int i = 0; i < 4; ++i) a0[i] = ldA(cur, i, 1);
#pragma unroll
    for (int j = 0; j < 4; ++j) b1[j] = ldB(cur, j, 1);
    stageA(nxt, 1, tn1);
    __builtin_amdgcn_s_barrier();
    asm volatile("s_waitcnt lgkmcnt(0)" ::: "memory");
    __builtin_amdgcn_sched_barrier(0);
    __builtin_amdgcn_s_setprio(1);
#pragma unroll
    for (int i = 0; i < 4; ++i)
#pragma unroll
      for (int j = 0; j < 4; ++j) acc[i][j] = mfma16(a0[i], b1[j], acc[i][j]);
    __builtin_amdgcn_s_setprio(0);
    asm volatile("s_waitcnt vmcnt(8)" ::: "memory");
    __builtin_amdgcn_s_barrier();

    // ---- ph3: (grp1, kc0) ----
#pragma unroll
    for (int i = 0; i < 4; ++i) a0[i] = ldA(cur, 4 + i, 0);
    stageA(cur, 0, tn2);
    __builtin_amdgcn_s_barrier();
    asm volatile("s_waitcnt lgkmcnt(0)" ::: "memory");
    __builtin_amdgcn_sched_barrier(0);
    __builtin_amdgcn_s_setprio(1);
#pragma unroll
    for (int i = 0; i < 4; ++i)
#pragma unroll
      for (int j = 0; j < 4; ++j) acc[4 + i][j] = mfma16(a0[i], b0[j], acc[4 + i][j]);
    __builtin_amdgcn_s_setprio(0);
    __builtin_amdgcn_s_barrier();

    // ---- ph4: (grp1, kc1) ----
#pragma unroll
    for (int i = 0; i < 4; ++i) a0[i] = ldA(cur, 4 + i, 1);
    stageB(cur, 0, tn2);
    __builtin_amdgcn_s_barrier();
    asm volatile("s_waitcnt lgkmcnt(0)" ::: "memory");
    __builtin_amdgcn_sched_barrier(0);
    __builtin_amdgcn_s_setprio(1);
#pragma unroll
    for (int i = 0; i < 4; ++i)
#pragma unroll
      for (int j = 0; j < 4; ++j) acc[4 + i][j] = mfma16(a0[i], b1[j], acc[4 + i][j]);
    __builtin_amdgcn_s_setprio(0);
    asm volatile("s_waitcnt vmcnt(6)" ::: "memory");
    __builtin_amdgcn_s_barrier();
  }

  // epilogue
#pragma unroll
  for (int mi = 0; mi < 8; ++mi) {
    int row = bm + wr * 128 + mi * 16 + g * 4;
#pragma unroll
    for (int j = 0; j < 4; ++j) {
      int col = bn + wc * 64 + j * 16 + l15;
      float bcv = biasCol ? biasCol[col] : 0.0f;
#pragma unroll
      for (int rr = 0; rr < 4; ++rr) {
        float brv = biasRow ? biasRow[row + rr] : 0.0f;
        float v = acc[mi][j][rr] + bcv + brv;
        if constexpr (sizeof(CT) == 1) {
          unsigned int p = __builtin_amdgcn_cvt_pk_fp8_f32(v, v, 0, false);
          C[(size_t)(row + rr) * ldc + col] = (CT)(p & 0xff);
        } else if constexpr (sizeof(CT) == 2) {
          C[(size_t)(row + rr) * ldc + col] = f2bf(v);
        } else {
          C[(size_t)(row + rr) * ldc + col] = v;
        }
      }
    }
  }
}

// ---- proj_qk: z=0 Q->fp8, z=1 K->fp8 (256 blocks, one full wave) ----
__global__ __launch_bounds__(512, 2) void proj_qk(
    const u16* __restrict__ prim_ctx, const u16* __restrict__ wqk,
    const float* __restrict__ bq, const float* __restrict__ bk,
    u8* __restrict__ qk8) {
  __shared__ u16 smem[4 * 16384];
  int bz = blockIdx.z;
  gemm_body<u8>(smem, smem + 2 * 16384,
                prim_ctx + (size_t)bz * 8192 * 1024,
                wqk + (size_t)bz * 1024 * 1024,
                bz ? bk : bq, nullptr,
                qk8 + (size_t)bz * 8192 * 1024,
                blockIdx.x * 256, blockIdx.y * 256, 1024, 1024, 1024, 1024);
}

// ---- fp8 S-GEMM (r13 schedule, split C): S = Q8 @ K8^T, bf16 out ----
__global__ __launch_bounds__(512, 2) void gemm_s8(
    const u8* __restrict__ A, const u8* __restrict__ Bt,
    u16* __restrict__ Clo, u16* __restrict__ Chi) {
  const int lda = 1024, ldb = 1024, ldc = 2048, K = 1024;
  int bz = blockIdx.z;
  const u8* Ab = A + (size_t)bz * 2048 * 1024;
  const u8* Bb = Bt + (size_t)bz * 2048 * 1024;
  u16* Cb = (bz < 2) ? Clo + (size_t)bz * 2048 * 2048
                     : Chi + (size_t)(bz - 2) * 2048 * 2048;
  int bm = blockIdx.x * 256, bn = blockIdx.y * 256;

  __shared__ u8 aLds[2][256 * 64];
  __shared__ u8 bLds[2][256 * 64];
  int tid = threadIdx.x;
  int lane = tid & 63, w = tid >> 6;
  int l15 = lane & 15, g = lane >> 4;
  int wr = w >> 2, wc = w & 3;
  int NT = K >> 6;

  f32x4 acc[8][4] = {};

  auto stageA = [&](int buf, int h, int tk) {
    int k0 = tk * 64;
    int r = tid >> 2;
    int row = h * 64 + (r & 63) + (r >> 6) * 128;
    int cd = (tid & 3) * 16;
    int cs = cd ^ ((row & 3) * 16);
    gload16(Ab + (size_t)(bm + row) * lda + k0 + cs, &aLds[buf][row * 64 + cd]);
  };
  auto stageB = [&](int buf, int x, int tk) {
    int k0 = tk * 64;
    int row = x * 128 + (tid >> 2);
    int cd = (tid & 3) * 16;
    int cs = cd ^ ((row & 3) * 16);
    gload16(Bb + (size_t)(bn + row) * ldb + k0 + cs, &bLds[buf][row * 64 + cd]);
  };
  auto ldA = [&](int buf, int m, int kc) -> long {
    int row = wr * 128 + m * 16 + l15;
    int colb = (kc * 32 + g * 8) ^ ((row & 3) * 16);
    return *(const long*)&aLds[buf][row * 64 + colb];
  };
  auto ldB = [&](int buf, int j, int kc) -> long {
    int row = wc * 64 + j * 16 + l15;
    int colb = (kc * 32 + g * 8) ^ ((row & 3) * 16);
    return *(const long*)&bLds[buf][row * 64 + colb];
  };

  stageA(0, 0, 0);
  stageB(0, 0, 0);
  stageB(0, 1, 0);
  stageA(0, 1, 0);
  int t1c = NT > 1 ? 1 : 0;
  stageA(1, 0, t1c);
  stageB(1, 0, t1c);
  asm volatile("s_waitcnt vmcnt(3)" ::: "memory");
  __builtin_amdgcn_s_barrier();

  for (int t = 0; t < NT; ++t) {
    int cur = t & 1, nxt = cur ^ 1;
    int tn1 = (t + 1 < NT) ? t + 1 : NT - 1;
    int tn2 = (t + 2 < NT) ? t + 2 : NT - 1;
    long a0[4], b0[4], b1[4];

#pragma unroll
    for (int i = 0; i < 4; ++i) a0[i] = ldA(cur, i, 0);
#pragma unroll
    for (int j = 0; j < 4; ++j) b0[j] = ldB(cur, j, 0);
    stageB(nxt, 1, tn1);
    __builtin_amdgcn_s_barrier();
    asm volatile("s_waitcnt lgkmcnt(0)" ::: "memory");
    __builtin_amdgcn_sched_barrier(0);
    __builtin_amdgcn_s_setprio(1);
#pragma unroll
    for (int i = 0; i < 4; ++i)
#pragma unroll
      for (int j = 0; j < 4; ++j)
        acc[i][j] = __builtin_amdgcn_mfma_f32_16x16x32_fp8_fp8(a0[i], b0[j], acc[i][j], 0, 0, 0);
    __builtin_amdgcn_s_setprio(0);
    __builtin_amdgcn_s_barrier();

#pragma unroll
    for (int i = 0; i < 4; ++i) a0[i] = ldA(cur, i, 1);
#pragma unroll
    for (int j = 0; j < 4; ++j) b1[j] = ldB(cur, j, 1);
    stageA(nxt, 1, tn1);
    __builtin_amdgcn_s_barrier();
    asm volatile("s_waitcnt lgkmcnt(0)" ::: "memory");
    __builtin_amdgcn_sched_barrier(0);
    __builtin_amdgcn_s_setprio(1);
#pragma unroll
    for (int i = 0; i < 4; ++i)
#pragma unroll
      for (int j = 0; j < 4; ++j)
        acc[i][j] = __builtin_amdgcn_mfma_f32_16x16x32_fp8_fp8(a0[i], b1[j], acc[i][j], 0, 0, 0);
    __builtin_amdgcn_s_setprio(0);
    asm volatile("s_waitcnt vmcnt(4)" ::: "memory");
    __builtin_amdgcn_s_barrier();

#pragma unroll
    for (int i = 0; i < 4; ++i) a0[i] = ldA(cur, 4 + i, 0);
    stageA(cur, 0, tn2);
    __builtin_amdgcn_s_barrier();
    asm volatile("s_waitcnt lgkmcnt(0)" ::: "memory");
    __builtin_amdgcn_sched_barrier(0);
    __builtin_amdgcn_s_setprio(1);
#pragma unroll
    for (int i = 0; i < 4; ++i)
#pragma unroll
      for (int j = 0; j < 4; ++j)
        acc[4 + i][j] = __builtin_amdgcn_mfma_f32_16x16x32_fp8_fp8(a0[i], b0[j], acc[4 + i][j], 0, 0, 0);
    __builtin_amdgcn_s_setprio(0);
    __builtin_amdgcn_s_barrier();

#pragma unroll
    for (int i = 0; i < 4; ++i) a0[i] = ldA(cur, 4 + i, 1);
    stageB(cur, 0, tn2);
    __builtin_amdgcn_s_barrier();
    asm volatile("s_waitcnt lgkmcnt(0)" ::: "memory");
    __builtin_amdgcn_sched_barrier(0);
    __builtin_amdgcn_s_setprio(1);
#pragma unroll
    for (int i = 0; i < 4; ++i)
#pragma unroll
      for (int j = 0; j < 4; ++j)
        acc[4 + i][j] = __builtin_amdgcn_mfma_f32_16x16x32_fp8_fp8(a0[i], b1[j], acc[4 + i][j], 0, 0, 0);
    __builtin_amdgcn_s_setprio(0);
    asm volatile("s_waitcnt vmcnt(3)" ::: "memory");
    __builtin_amdgcn_s_barrier();
  }

#pragma unroll
  for (int mi = 0; mi < 8; ++mi) {
    int row = bm + wr * 128 + mi * 16 + g * 4;
#pragma unroll
    for (int j = 0; j < 4; ++j) {
      int col = bn + wc * 64 + j * 16 + l15;
#pragma unroll
      for (int rr = 0; rr < 4; ++rr)
        Cb[(size_t)(row + rr) * ldc + col] = f2bf(acc[mi][j][rr]);
    }
  }
}

// ---- merged V^T projection + in-place softmax (1152 blocks x 512 threads) ----
// blocks 0..127:    V^T = Wv^T*ctx^T + bv(row) -> vt [1024 x 8192]
// blocks 128..1151: wave-per-row softmax on S in place (wave reads its full
// row into registers before writing -> in-place safe). rows 0..8191.
__global__ __launch_bounds__(512, 2) void vt_softmax(
    const u16* __restrict__ wvt, const u16* __restrict__ ctx_bf,
    const float* __restrict__ bv, u16* __restrict__ vt,
    u16* __restrict__ Slo, u16* __restrict__ Shi,
    const float* __restrict__ mask) {
  __shared__ u16 smem[4 * 16384];
  int b = blockIdx.x;
  if (b < 128) {
    gemm_body<u16>(smem, smem + 2 * 16384, wvt, ctx_bf, nullptr, bv, vt,
                   (b & 3) * 256, (b >> 2) * 256, 1024, 1024, 1024, 8192);
    return;
  }
  const float C1 = 0.04508422f;    // log2(e)/32
  const float C2 = -1.4426950e9f;  // -1e9*log2(e)
  int row = (b - 128) * 8 + (threadIdx.x >> 6);
  int lane = threadIdx.x & 63;
  u16* sp = (row < 4096) ? Slo + (size_t)row * 2048
                         : Shi + (size_t)(row - 4096) * 2048;
  const float* mp = mask + (size_t)row * 2048;

  float a[32];
#pragma unroll
  for (int pass = 0; pass < 4; ++pass) {
    int e0 = pass * 512 + lane * 8;
    u16x8 sv = *(const u16x8*)(sp + e0);
    float4 m0 = *(const float4*)(mp + e0);
    float4 m1 = *(const float4*)(mp + e0 + 4);
    a[pass * 8 + 0] = bf2f(sv[0]) * C1 + m0.x * C2;
    a[pass * 8 + 1] = bf2f(sv[1]) * C1 + m0.y * C2;
    a[pass * 8 + 2] = bf2f(sv[2]) * C1 + m0.z * C2;
    a[pass * 8 + 3] = bf2f(sv[3]) * C1 + m0.w * C2;
    a[pass * 8 + 4] = bf2f(sv[4]) * C1 + m1.x * C2;
    a[pass * 8 + 5] = bf2f(sv[5]) * C1 + m1.y * C2;
    a[pass * 8 + 6] = bf2f(sv[6]) * C1 + m1.z * C2;
    a[pass * 8 + 7] = bf2f(sv[7]) * C1 + m1.w * C2;
  }
  float m = a[0];
#pragma unroll
  for (int i = 1; i < 32; ++i) m = fmaxf(m, a[i]);
#pragma unroll
  for (int off = 32; off >= 1; off >>= 1) m = fmaxf(m, __shfl_xor(m, off));

  float s = 0.0f;
#pragma unroll
  for (int i = 0; i < 32; ++i) {
    a[i] = exp2f(a[i] - m);
    s += a[i];
  }
#pragma unroll
  for (int off = 32; off >= 1; off >>= 1) s += __shfl_xor(s, off);
  float inv = 1.0f / s;

#pragma unroll
  for (int pass = 0; pass < 4; ++pass) {
    int e0 = pass * 512 + lane * 8;
    u16x8 o;
#pragma unroll
    for (int j = 0; j < 8; ++j) o[j] = f2bf(a[pass * 8 + j] * inv);
    *(u16x8*)(sp + e0) = o;
  }
}

// ---- PV: O = P @ (V^T)^T, A (P) split across two regions ----
__global__ __launch_bounds__(512, 2) void gemm_pv(
    const u16* __restrict__ Alo, const u16* __restrict__ Ahi,
    const u16* __restrict__ Bt, float* __restrict__ C) {
  __shared__ u16 smem[4 * 16384];
  int bz = blockIdx.z;
  const u16* A = (bz < 2) ? Alo + (size_t)bz * 2048 * 2048
                          : Ahi + (size_t)(bz - 2) * 2048 * 2048;
  gemm_body<float>(smem, smem + 2 * 16384, A, Bt + (size_t)bz * 2048,
                   nullptr, nullptr, C + (size_t)bz * 2048 * 1024,
                   blockIdx.x * 256, blockIdx.y * 256, 2048, 2048, 8192, 1024);
}

extern "C" void kernel_launch(void* const* d_in, const int* in_sizes, int n_in,
                              void* d_out, int out_size, void* d_ws, size_t ws_size,
                              hipStream_t stream) {
  const float* primary = (const float*)d_in[0];
  const float* ctx     = (const float*)d_in[1];
  const float* mask    = (const float*)d_in[2];
  const float* Wq      = (const float*)d_in[3];
  const float* bq      = (const float*)d_in[4];
  const float* Wk      = (const float*)d_in[5];
  const float* bk      = (const float*)d_in[6];
  const float* Wv      = (const float*)d_in[7];
  const float* bv      = (const float*)d_in[8];
  float* out = (float*)d_out;

  char* ws = (char*)d_ws;
  // Slot map (peak 90.2 MB, P computed IN PLACE over S):
  //   [0, 16.8M)    prim_bf (cvt->proj_qk)  -> sbf_lo = P_lo (S batches 0,1)
  //   [16.8, 33.5M) ctx_bf  (cvt->proj_qk K, vt_softmax V^T)
  //   [33.5, 50.3M) q8,k8   (proj_qk->s8)
  //   [50.3, 67M)   vtbf    (vt_softmax->PV)
  //   [67, 83.9M)   sbf_hi = P_hi (S batches 2,3)
  //   [83.9, 90.2M) wqt/wkt/wvt (wqt,wkt contiguous)
  u16* prim_bf = (u16*)(ws);
  u16* ctx_bf  = (u16*)(ws + 16777216);
  u8*  qk8     = (u8*)(ws + 2 * 16777216);
  u16* vtbf    = (u16*)(ws + 3 * 16777216);
  u16* sbf_lo  = (u16*)(ws);                      // over prim_bf (dead)
  u16* sbf_hi  = (u16*)(ws + 4 * 16777216);
  u16* wqt     = (u16*)(ws + 5 * 16777216);
  u16* wkt     = (u16*)(ws + 5 * 16777216 + 2097152);
  u16* wvt     = (u16*)(ws + 5 * 16777216 + 2 * 2097152);

  // 1. converts + weight transposes
  cvt_wt<<<5120, 256, 0, stream>>>(primary, prim_bf, ctx, ctx_bf,
                                   Wq, Wk, Wv, wqt, wkt, wvt);
  // 2. Q,K -> fp8 (256 blocks, one full wave)
  proj_qk<<<dim3(32, 4, 2), 512, 0, stream>>>(prim_bf, wqt, bq, bk, qk8);
  // 3. S = Q8 @ K8^T -> sbf_lo/hi bf16 (fp8 staging)
  gemm_s8<<<dim3(8, 8, 4), 512, 0, stream>>>(qk8, qk8 + 8192 * 1024,
                                             sbf_lo, sbf_hi);
  // 4. V^T projection (128 blocks) overlapped with in-place softmax (1024 blocks)
  vt_softmax<<<1152, 512, 0, stream>>>(wvt, ctx_bf, bv, vtbf,
                                       sbf_lo, sbf_hi, mask);
  // 5. O = P @ V -> out fp32
  gemm_pv<<<dim3(8, 4, 4), 512, 0, stream>>>(sbf_lo, sbf_hi, vtbf, out);
}